// Round 1
// baseline (116.375 us; speedup 1.0000x reference)
//
#include <hip/hip_runtime.h>
#include <math.h>

// Hungarian matcher cost matrix:
//   C[n,t] = 5*L1(xyxy) + 2*(pos-neg focal @ label[t]) - 2*GIoU + 9999*inner
// N = bs*nq = 14400, T = 1024, C(classes) = 91.  Output [N,T] f32 (59 MB).
//
// Design: one fused kernel. Block = 256 threads handles BN=16 rows x BT=256
// target columns. Phase 1 stages per-row data (xyxy, point, area) and the
// focal class-cost table (BN x C) into LDS; phase 2 each thread owns one t
// column (target box/label in registers) and loops the 16 rows, gathering the
// class cost from LDS and writing coalesced dwords.

#define BN 16
#define BT 256
#define TBL_STRIDE 128   // >= C, pow2 so index is shift+or

__global__ __launch_bounds__(BT) void matcher_kernel(
    const float* __restrict__ logits,   // [N, C]
    const float* __restrict__ boxes,    // [N, 4] cxcywh
    const float* __restrict__ points,   // [N, 2]
    const float* __restrict__ objs,     // [N, 1]
    const int*   __restrict__ labels,   // [T]
    const float* __restrict__ tboxes,   // [T, 4] cxcywh
    float* __restrict__ out,            // [N, T]
    int N, int C, int T)
{
    __shared__ float s_table[BN * TBL_STRIDE]; // focal class cost per (row, class)
    __shared__ float s_row[BN][8];             // x0,y0,x1,y1,px,py,area1,(pad)

    const int tid = threadIdx.x;
    const int rowBase = blockIdx.y * BN;
    const int t = blockIdx.x * BT + tid;

    // ---- Phase 1a: per-row constants (16 threads) ----
    if (tid < BN) {
        int n = rowBase + tid;
        if (n < N) {
            float4 b = *(const float4*)(boxes + 4 * n);
            float x0 = b.x - 0.5f * b.z;
            float y0 = b.y - 0.5f * b.w;
            float x1 = b.x + 0.5f * b.z;
            float y1 = b.y + 0.5f * b.w;
            s_row[tid][0] = x0;
            s_row[tid][1] = y0;
            s_row[tid][2] = x1;
            s_row[tid][3] = y1;
            float2 p = *(const float2*)(points + 2 * n);
            s_row[tid][4] = p.x;
            s_row[tid][5] = p.y;
            s_row[tid][6] = (x1 - x0) * (y1 - y0);
        }
    }

    // ---- Phase 1b: focal class-cost table for this block's rows ----
    // pos - neg, with p = sigmoid(logit) * sigmoid(obj), gamma = 2 (p^g = p*p)
    for (int idx = tid; idx < BN * C; idx += BT) {
        int r = idx / C;
        int c = idx - r * C;
        int n = rowBase + r;
        float v = 0.0f;
        if (n < N) {
            float lg = logits[n * C + c];
            float ps = 1.0f / (1.0f + expf(-lg));
            float po = 1.0f / (1.0f + expf(-objs[n]));
            float p = ps * po;
            float omp = 1.0f - p;
            float pos = 0.25f * (omp * omp) * (-logf(p + 1e-8f));
            float neg = 0.75f * (p * p) * (-logf(omp + 1e-8f));
            v = pos - neg;
        }
        s_table[r * TBL_STRIDE + c] = v;
    }

    __syncthreads();

    // ---- Phase 2: per-target column ----
    if (t < T) {
        float4 tb = *(const float4*)(tboxes + 4 * t);
        float tx0 = tb.x - 0.5f * tb.z;
        float ty0 = tb.y - 0.5f * tb.w;
        float tx1 = tb.x + 0.5f * tb.z;
        float ty1 = tb.y + 0.5f * tb.w;
        float tarea = (tx1 - tx0) * (ty1 - ty0);
        int lab = labels[t];

        #pragma unroll
        for (int r = 0; r < BN; ++r) {
            int n = rowBase + r;
            if (n < N) {
                float x0 = s_row[r][0], y0 = s_row[r][1];
                float x1 = s_row[r][2], y1 = s_row[r][3];
                float px = s_row[r][4], py = s_row[r][5];
                float a1 = s_row[r][6];
                float cc = s_table[r * TBL_STRIDE + lab];

                // L1 on xyxy
                float l1 = fabsf(x0 - tx0) + fabsf(y0 - ty0)
                         + fabsf(x1 - tx1) + fabsf(y1 - ty1);

                // GIoU
                float ix0 = fmaxf(x0, tx0), iy0 = fmaxf(y0, ty0);
                float ix1 = fminf(x1, tx1), iy1 = fminf(y1, ty1);
                float iw = fmaxf(ix1 - ix0, 0.0f);
                float ih = fmaxf(iy1 - iy0, 0.0f);
                float inter = iw * ih;
                float uni = a1 + tarea - inter;
                float iou = inter / uni;
                float cx0 = fminf(x0, tx0), cy0 = fminf(y0, ty0);
                float cx1 = fmaxf(x1, tx1), cy1 = fmaxf(y1, ty1);
                float cw = fmaxf(cx1 - cx0, 0.0f);
                float ch = fmaxf(cy1 - cy0, 0.0f);
                float carea = cw * ch;
                float giou = iou - (carea - uni) / carea;

                // inner-point (exact same op sequence as reference => same sign)
                float left = px - tx0;
                float top = py - ty0;
                float right = tx1 - px;
                float bottom = ty1 - py;
                float mind = fminf(fminf(left, top), fminf(right, bottom));
                float inner = (mind >= 0.0f) ? 0.0f : 1.0f;

                float Cv = 5.0f * l1 + 2.0f * cc - 2.0f * giou + 9999.0f * inner;
                out[n * T + t] = Cv;
            }
        }
    }
}

extern "C" void kernel_launch(void* const* d_in, const int* in_sizes, int n_in,
                              void* d_out, int out_size, void* d_ws, size_t ws_size,
                              hipStream_t stream) {
    const float* logits = (const float*)d_in[0];  // [bs,nq,nc]
    const float* boxes  = (const float*)d_in[1];  // [bs,nq,4]
    const float* points = (const float*)d_in[2];  // [bs,nq,2]
    const float* objs   = (const float*)d_in[3];  // [bs,nq,1]
    const int*   labels = (const int*)d_in[4];    // [T]
    const float* tboxes = (const float*)d_in[5];  // [T,4]
    float* out = (float*)d_out;

    int N = in_sizes[1] / 4;        // 14400
    int T = in_sizes[5] / 4;        // 1024
    int C = in_sizes[0] / N;        // 91

    dim3 grid((T + BT - 1) / BT, (N + BN - 1) / BN);
    matcher_kernel<<<grid, BT, 0, stream>>>(logits, boxes, points, objs,
                                            labels, tboxes, out, N, C, T);
}

// Round 2
// 101.187 us; speedup vs baseline: 1.1501x; 1.1501x over previous
//
#include <hip/hip_runtime.h>
#include <math.h>

// Hungarian matcher cost matrix:
//   C[n,t] = 5*L1(xyxy) + 2*(focal@label[t]) - 2*GIoU + 9999*inner
// N = 14400, T = 1024, C = 91. Output [N,T] f32 (59 MB).
//
// R2: VALU-bound per rocprof (VALUBusy 78%, HBM 15%).
//  - __builtin_amdgcn_rcpf replaces both IEEE f32 divides (~20 VALU -> ~4)
//  - each thread owns VT=4 consecutive t columns: float4 stores, target data
//    in registers, per-row LDS broadcast amortized 4x
//  - one block = 16 rows x all 1024 columns -> grid 900, table built once/row
//  - obj sigmoid hoisted per-row; dead enclosing-box clamps removed (w,h>=0)

#define BN 16
#define BT 256
#define VT 4
#define TBL_STRIDE 96   // >= C, 16B-multiple

__global__ __launch_bounds__(BT) void matcher_kernel(
    const float* __restrict__ logits,   // [N, C]
    const float* __restrict__ boxes,    // [N, 4] cxcywh
    const float* __restrict__ points,   // [N, 2]
    const float* __restrict__ objs,     // [N, 1]
    const int*   __restrict__ labels,   // [T]
    const float* __restrict__ tboxes,   // [T, 4] cxcywh
    float* __restrict__ out,            // [N, T]
    int N, int C, int T)
{
    __shared__ float s_table[BN * TBL_STRIDE]; // focal class cost per (row, class)
    __shared__ float s_row[BN][8];             // x0,y0,x1,y1 | px,py,area1,po

    const int tid = threadIdx.x;
    const int rowBase = blockIdx.y * BN;
    const int t0 = (blockIdx.x * BT + tid) * VT;

    // ---- Phase 1a: per-row constants ----
    if (tid < BN) {
        int n = rowBase + tid;
        if (n < N) {
            float4 b = *(const float4*)(boxes + 4 * n);
            float x0 = b.x - 0.5f * b.z;
            float y0 = b.y - 0.5f * b.w;
            float x1 = b.x + 0.5f * b.z;
            float y1 = b.y + 0.5f * b.w;
            s_row[tid][0] = x0;
            s_row[tid][1] = y0;
            s_row[tid][2] = x1;
            s_row[tid][3] = y1;
            float2 p = *(const float2*)(points + 2 * n);
            s_row[tid][4] = p.x;
            s_row[tid][5] = p.y;
            s_row[tid][6] = (x1 - x0) * (y1 - y0);
            s_row[tid][7] = 1.0f / (1.0f + expf(-objs[n]));  // obj sigmoid
        }
    }
    __syncthreads();

    // ---- Phase 1b: focal class-cost table (pos - neg) for this block's rows ----
    for (int idx = tid; idx < BN * C; idx += BT) {
        int r = idx / C;
        int c = idx - r * C;
        int n = rowBase + r;
        float v = 0.0f;
        if (n < N) {
            float lg = logits[n * C + c];
            float ps = 1.0f / (1.0f + expf(-lg));
            float p = ps * s_row[r][7];
            float omp = 1.0f - p;
            float pos = 0.25f * (omp * omp) * (-logf(p + 1e-8f));
            float neg = 0.75f * (p * p) * (-logf(omp + 1e-8f));
            v = pos - neg;
        }
        s_table[r * TBL_STRIDE + c] = v;
    }
    __syncthreads();

    // ---- Phase 2: 4 target columns per thread ----
    if (t0 + VT <= T) {
        float tx0[VT], ty0[VT], tx1[VT], ty1[VT], tarea[VT];
        int lab[VT];
        int4 lv = *(const int4*)(labels + t0);
        lab[0] = lv.x; lab[1] = lv.y; lab[2] = lv.z; lab[3] = lv.w;
        #pragma unroll
        for (int j = 0; j < VT; ++j) {
            float4 tb = *(const float4*)(tboxes + 4 * (t0 + j));
            tx0[j] = tb.x - 0.5f * tb.z;
            ty0[j] = tb.y - 0.5f * tb.w;
            tx1[j] = tb.x + 0.5f * tb.z;
            ty1[j] = tb.y + 0.5f * tb.w;
            tarea[j] = (tx1[j] - tx0[j]) * (ty1[j] - ty0[j]);
        }

        #pragma unroll
        for (int r = 0; r < BN; ++r) {
            int n = rowBase + r;
            if (n >= N) continue;          // wave-uniform scalar branch
            float4 ra = *(const float4*)&s_row[r][0]; // x0,y0,x1,y1 (broadcast)
            float4 rb = *(const float4*)&s_row[r][4]; // px,py,a1,po
            float x0 = ra.x, y0 = ra.y, x1 = ra.z, y1 = ra.w;
            float px = rb.x, py = rb.y, a1 = rb.z;
            const float* trow = s_table + r * TBL_STRIDE;

            float4 res;
            float* resp = (float*)&res;
            #pragma unroll
            for (int j = 0; j < VT; ++j) {
                float cc = trow[lab[j]];

                // L1 on xyxy (abs folds into operand modifiers)
                float l1 = fabsf(x0 - tx0[j]) + fabsf(y0 - ty0[j])
                         + fabsf(x1 - tx1[j]) + fabsf(y1 - ty1[j]);

                // intersection / union
                float iw = fminf(x1, tx1[j]) - fmaxf(x0, tx0[j]);
                float ih = fminf(y1, ty1[j]) - fmaxf(y0, ty0[j]);
                float inter = fmaxf(iw, 0.0f) * fmaxf(ih, 0.0f);
                float uni = (a1 + tarea[j]) - inter;
                float iou = inter * __builtin_amdgcn_rcpf(uni);

                // enclosing box (extents provably >= 0: w,h >= 0)
                float cw = fmaxf(x1, tx1[j]) - fminf(x0, tx0[j]);
                float ch = fmaxf(y1, ty1[j]) - fminf(y0, ty0[j]);
                float carea = cw * ch;
                float giou = iou - (carea - uni) * __builtin_amdgcn_rcpf(carea);

                // inner-point: exact reference op sequence (sign-exact)
                float left = px - tx0[j];
                float top = py - ty0[j];
                float right = tx1[j] - px;
                float bottom = ty1[j] - py;
                float mind = fminf(fminf(left, top), fminf(right, bottom));

                float Cv = fmaf(5.0f, l1, fmaf(2.0f, cc, -2.0f * giou));
                Cv += (mind >= 0.0f) ? 0.0f : 9999.0f;
                resp[j] = Cv;
            }
            *(float4*)(out + (size_t)n * T + t0) = res;
        }
    }
}

extern "C" void kernel_launch(void* const* d_in, const int* in_sizes, int n_in,
                              void* d_out, int out_size, void* d_ws, size_t ws_size,
                              hipStream_t stream) {
    const float* logits = (const float*)d_in[0];  // [bs,nq,nc]
    const float* boxes  = (const float*)d_in[1];  // [bs,nq,4]
    const float* points = (const float*)d_in[2];  // [bs,nq,2]
    const float* objs   = (const float*)d_in[3];  // [bs,nq,1]
    const int*   labels = (const int*)d_in[4];    // [T]
    const float* tboxes = (const float*)d_in[5];  // [T,4]
    float* out = (float*)d_out;

    int N = in_sizes[1] / 4;        // 14400
    int T = in_sizes[5] / 4;        // 1024
    int C = in_sizes[0] / N;        // 91

    dim3 grid((T + BT * VT - 1) / (BT * VT), (N + BN - 1) / BN);
    matcher_kernel<<<grid, BT, 0, stream>>>(logits, boxes, points, objs,
                                            labels, tboxes, out, N, C, T);
}

// Round 3
// 98.545 us; speedup vs baseline: 1.1809x; 1.0268x over previous
//
#include <hip/hip_runtime.h>
#include <math.h>

// Hungarian matcher cost matrix:
//   C[n,t] = 5*L1(xyxy) + 2*(focal@label[t]) - 2*GIoU + 9999*inner
// N = 14400, T = 1024, C = 91. Output [N,T] f32 (59 MB).
//
// R3: latency/occupancy-bound per rocprof (VALU 32%, HBM 16%, occ 33%,
// grid was 900 blocks = 3.5/CU). Split ROWS not columns (table work is
// per-row, so row-split duplicates nothing): BN 16->8, grid 1800 blocks
// = 7.0 blocks/CU (cap is 8 for 256-thr blocks), ~28 waves/CU.

#define BN 8
#define BT 256
#define VT 4
#define TBL_STRIDE 96   // >= C, 16B-multiple

__global__ __launch_bounds__(BT) void matcher_kernel(
    const float* __restrict__ logits,   // [N, C]
    const float* __restrict__ boxes,    // [N, 4] cxcywh
    const float* __restrict__ points,   // [N, 2]
    const float* __restrict__ objs,     // [N, 1]
    const int*   __restrict__ labels,   // [T]
    const float* __restrict__ tboxes,   // [T, 4] cxcywh
    float* __restrict__ out,            // [N, T]
    int N, int C, int T)
{
    __shared__ float s_table[BN * TBL_STRIDE]; // focal class cost per (row, class)
    __shared__ float s_row[BN][8];             // x0,y0,x1,y1 | px,py,area1,po

    const int tid = threadIdx.x;
    const int rowBase = blockIdx.y * BN;
    const int t0 = (blockIdx.x * BT + tid) * VT;

    // ---- Phase 1a: per-row constants ----
    if (tid < BN) {
        int n = rowBase + tid;
        if (n < N) {
            float4 b = *(const float4*)(boxes + 4 * n);
            float x0 = b.x - 0.5f * b.z;
            float y0 = b.y - 0.5f * b.w;
            float x1 = b.x + 0.5f * b.z;
            float y1 = b.y + 0.5f * b.w;
            s_row[tid][0] = x0;
            s_row[tid][1] = y0;
            s_row[tid][2] = x1;
            s_row[tid][3] = y1;
            float2 p = *(const float2*)(points + 2 * n);
            s_row[tid][4] = p.x;
            s_row[tid][5] = p.y;
            s_row[tid][6] = (x1 - x0) * (y1 - y0);
            s_row[tid][7] = 1.0f / (1.0f + expf(-objs[n]));  // obj sigmoid
        }
    }
    __syncthreads();

    // ---- Phase 1b: focal class-cost table (pos - neg) for this block's rows ----
    for (int idx = tid; idx < BN * C; idx += BT) {
        int r = idx / C;
        int c = idx - r * C;
        int n = rowBase + r;
        float v = 0.0f;
        if (n < N) {
            float lg = logits[n * C + c];
            float ps = 1.0f / (1.0f + expf(-lg));
            float p = ps * s_row[r][7];
            float omp = 1.0f - p;
            float pos = 0.25f * (omp * omp) * (-logf(p + 1e-8f));
            float neg = 0.75f * (p * p) * (-logf(omp + 1e-8f));
            v = pos - neg;
        }
        s_table[r * TBL_STRIDE + c] = v;
    }
    __syncthreads();

    // ---- Phase 2: 4 target columns per thread, BN rows ----
    if (t0 + VT <= T) {
        float tx0[VT], ty0[VT], tx1[VT], ty1[VT], tarea[VT];
        int lab[VT];
        int4 lv = *(const int4*)(labels + t0);
        lab[0] = lv.x; lab[1] = lv.y; lab[2] = lv.z; lab[3] = lv.w;
        #pragma unroll
        for (int j = 0; j < VT; ++j) {
            float4 tb = *(const float4*)(tboxes + 4 * (t0 + j));
            tx0[j] = tb.x - 0.5f * tb.z;
            ty0[j] = tb.y - 0.5f * tb.w;
            tx1[j] = tb.x + 0.5f * tb.z;
            ty1[j] = tb.y + 0.5f * tb.w;
            tarea[j] = (tx1[j] - tx0[j]) * (ty1[j] - ty0[j]);
        }

        #pragma unroll
        for (int r = 0; r < BN; ++r) {
            int n = rowBase + r;
            if (n >= N) continue;          // wave-uniform scalar branch
            float4 ra = *(const float4*)&s_row[r][0]; // x0,y0,x1,y1 (broadcast)
            float4 rb = *(const float4*)&s_row[r][4]; // px,py,a1,po
            float x0 = ra.x, y0 = ra.y, x1 = ra.z, y1 = ra.w;
            float px = rb.x, py = rb.y, a1 = rb.z;
            const float* trow = s_table + r * TBL_STRIDE;

            float4 res;
            float* resp = (float*)&res;
            #pragma unroll
            for (int j = 0; j < VT; ++j) {
                float cc = trow[lab[j]];

                // L1 on xyxy (abs folds into operand modifiers)
                float l1 = fabsf(x0 - tx0[j]) + fabsf(y0 - ty0[j])
                         + fabsf(x1 - tx1[j]) + fabsf(y1 - ty1[j]);

                // intersection / union
                float iw = fminf(x1, tx1[j]) - fmaxf(x0, tx0[j]);
                float ih = fminf(y1, ty1[j]) - fmaxf(y0, ty0[j]);
                float inter = fmaxf(iw, 0.0f) * fmaxf(ih, 0.0f);
                float uni = (a1 + tarea[j]) - inter;
                float iou = inter * __builtin_amdgcn_rcpf(uni);

                // enclosing box (extents provably >= 0: w,h >= 0)
                float cw = fmaxf(x1, tx1[j]) - fminf(x0, tx0[j]);
                float ch = fmaxf(y1, ty1[j]) - fminf(y0, ty0[j]);
                float carea = cw * ch;
                float giou = iou - (carea - uni) * __builtin_amdgcn_rcpf(carea);

                // inner-point: exact reference op sequence (sign-exact)
                float left = px - tx0[j];
                float top = py - ty0[j];
                float right = tx1[j] - px;
                float bottom = ty1[j] - py;
                float mind = fminf(fminf(left, top), fminf(right, bottom));

                float Cv = fmaf(5.0f, l1, fmaf(2.0f, cc, -2.0f * giou));
                Cv += (mind >= 0.0f) ? 0.0f : 9999.0f;
                resp[j] = Cv;
            }
            *(float4*)(out + (size_t)n * T + t0) = res;
        }
    }
}

extern "C" void kernel_launch(void* const* d_in, const int* in_sizes, int n_in,
                              void* d_out, int out_size, void* d_ws, size_t ws_size,
                              hipStream_t stream) {
    const float* logits = (const float*)d_in[0];  // [bs,nq,nc]
    const float* boxes  = (const float*)d_in[1];  // [bs,nq,4]
    const float* points = (const float*)d_in[2];  // [bs,nq,2]
    const float* objs   = (const float*)d_in[3];  // [bs,nq,1]
    const int*   labels = (const int*)d_in[4];    // [T]
    const float* tboxes = (const float*)d_in[5];  // [T,4]
    float* out = (float*)d_out;

    int N = in_sizes[1] / 4;        // 14400
    int T = in_sizes[5] / 4;        // 1024
    int C = in_sizes[0] / N;        // 91

    dim3 grid((T + BT * VT - 1) / (BT * VT), (N + BN - 1) / BN);
    matcher_kernel<<<grid, BT, 0, stream>>>(logits, boxes, points, objs,
                                            labels, tboxes, out, N, C, T);
}